// Round 2
// baseline (363.109 us; speedup 1.0000x reference)
//
#include <hip/hip_runtime.h>
#include <cstdint>
#include <cstddef>

// Problem constants
#define NB   32    // query batch
#define NSUP 25    // support images
#define KCLS 5     // classes
#define NC   512   // input channels
#define ND   128   // dk = dv
#define NP   196   // h*w
#define JS   208   // per-support padded row/col count (13*16)
#define NIMG 57    // 32 query + 25 support
#define CLS_COLS 1040   // 5*208 padded per-class col domain
#define NCHUNK 33       // 32-col chunks covering 1056 (last 16 cols pad)
#define SHIFT 8.0f      // fixed logit shift (softmax-invariant; overflow guard)

typedef __attribute__((ext_vector_type(8))) short short8;   // 8 x bf16 (4 VGPRs)
typedef __attribute__((ext_vector_type(4))) float floatx4;  // MFMA C/D

__device__ inline short f2bf(float x) {
  union { float f; uint32_t u; } v; v.f = x;
  uint32_t r = (v.u + 0x7FFFu + ((v.u >> 16) & 1u)) >> 16;  // RNE
  return (short)(r & 0xFFFFu);
}
__device__ inline float bf2f(short h) {
  union { uint32_t u; float f; } v; v.u = ((uint32_t)(uint16_t)h) << 16;
  return v.f;
}

// ---------------------------------------------------------------------------
// Kernel 0: fp32 -> bf16 hi/lo conversion + transpose.
//   Xhi/Xlo[img][pp:208][c:512]  (c-contiguous; pad rows = copy of row 195)
//   Whi/Wlo[mat][d:128][c:512]   (layout preserved)
// grid = 57 imgs * 8 c-slabs + 2 W blocks = 458 blocks x 256 threads.
// ---------------------------------------------------------------------------
__global__ __launch_bounds__(256) void conv_kernel(
    const float* __restrict__ supp, const float* __restrict__ qry,
    const float* __restrict__ Wqk, const float* __restrict__ Wv,
    uint16_t* __restrict__ Xhi, uint16_t* __restrict__ Xlo,
    uint16_t* __restrict__ Whi, uint16_t* __restrict__ Wlo)
{
  const int bx = blockIdx.x, tid = (int)threadIdx.x;
  if (bx >= 456) {                    // W conversion
    const int mat = bx - 456;
    const float* __restrict__ W = mat ? Wv : Wqk;
    uint16_t* dh = Whi + (size_t)mat * ND * NC;
    uint16_t* dl = Wlo + (size_t)mat * ND * NC;
    for (int i = tid; i < ND * NC; i += 256) {
      const float x = W[i];
      const short h = f2bf(x);
      dh[i] = (uint16_t)h;
      dl[i] = (uint16_t)f2bf(x - bf2f(h));
    }
    return;
  }
  __shared__ float lds[64 * 209];     // 64 c-rows x 208 p (+1 pad), 53.5 KB
  const int img = bx >> 3, c0 = (bx & 7) * 64;
  const float* __restrict__ X = (img < NB)
      ? (qry  + (size_t)img * NC * NP)
      : (supp + (size_t)(img - NB) * NC * NP);
  for (int idx = tid; idx < 64 * JS; idx += 256) {   // read [c][p] coalesced
    const int cc = idx / JS, pp = idx - cc * JS;
    const int ps = pp < NP ? pp : NP - 1;            // pad rows = row 195
    lds[cc * 209 + pp] = X[(c0 + cc) * NP + ps];
  }
  __syncthreads();
  for (int idx = tid; idx < 64 * JS; idx += 256) {   // write [p][c] coalesced
    const int cc = idx & 63, pp = idx >> 6;
    const float x = lds[cc * 209 + pp];
    const short h = f2bf(x);
    const size_t o = ((size_t)img * JS + pp) * NC + c0 + cc;
    Xhi[o] = (uint16_t)h;
    Xlo[o] = (uint16_t)f2bf(x - bf2f(h));
  }
}

// ---------------------------------------------------------------------------
// Kernel 1: projection GEMM, bf16 MFMA 16x16x32, 3-term hi/lo (~fp32 acc).
// qk-waves (bx < 741 = 57*13): A=X[p][c], B=Wqk[d][c] -> D[p][d];
//   direct coalesced stores to Qt[b][p][d] / Kt[n][j][d].
// v-waves  (456 = 57*8):       A=Wv[d][c], B=X[p][c] -> D[d][p];
//   direct coalesced stores to Vt[n][d][j] / outVq[b][d][p] (fp32).
// One wave per block.
// ---------------------------------------------------------------------------
__global__ __launch_bounds__(64) void gemm_kernel(
    const uint16_t* __restrict__ Xhi, const uint16_t* __restrict__ Xlo,
    const uint16_t* __restrict__ Whi, const uint16_t* __restrict__ Wlo,
    uint16_t* __restrict__ Qt, uint16_t* __restrict__ Kt,
    uint16_t* __restrict__ Vt, float* __restrict__ outVq)
{
  const int bx = blockIdx.x;
  const int lane = (int)threadIdx.x;
  const int ln = lane & 15, q = lane >> 4;

  if (bx < 741) {  // ---- qk path: img, p-tile ----
    const int img = bx / 13, mt = bx % 13;
    const size_t xrow = ((size_t)img * JS + mt * 16 + ln) * NC + q * 8;
    floatx4 acc[8];
    #pragma unroll
    for (int nt = 0; nt < 8; ++nt) acc[nt] = (floatx4){0.f, 0.f, 0.f, 0.f};

    for (int ks = 0; ks < 16; ++ks) {
      const short8 ah = *(const short8*)(Xhi + xrow + ks * 32);
      const short8 al = *(const short8*)(Xlo + xrow + ks * 32);
      #pragma unroll
      for (int nt = 0; nt < 8; ++nt) {
        const size_t wrow = (size_t)(nt * 16 + ln) * NC + ks * 32 + q * 8;
        const short8 bh = *(const short8*)(Whi + wrow);
        const short8 bl = *(const short8*)(Wlo + wrow);
        acc[nt] = __builtin_amdgcn_mfma_f32_16x16x32_bf16(al, bh, acc[nt], 0, 0, 0);
        acc[nt] = __builtin_amdgcn_mfma_f32_16x16x32_bf16(ah, bl, acc[nt], 0, 0, 0);
        acc[nt] = __builtin_amdgcn_mfma_f32_16x16x32_bf16(ah, bh, acc[nt], 0, 0, 0);
      }
    }
    // D row = p = mt*16 + q*4 + r, col = d = nt*16 + ln
    if (img < NB) {
      #pragma unroll
      for (int nt = 0; nt < 8; ++nt)
        #pragma unroll
        for (int r = 0; r < 4; ++r) {
          const int p = mt * 16 + q * 4 + r;
          if (p < NP)
            Qt[((size_t)img * NP + p) * ND + nt * 16 + ln] = (uint16_t)f2bf(acc[nt][r]);
        }
    } else {
      const int n = img - NB;
      #pragma unroll
      for (int nt = 0; nt < 8; ++nt)
        #pragma unroll
        for (int r = 0; r < 4; ++r) {
          const int p = mt * 16 + q * 4 + r;   // 0..207, pad rows masked in attn
          Kt[((size_t)n * JS + p) * ND + nt * 16 + ln] = (uint16_t)f2bf(acc[nt][r]);
        }
    }
  } else {  // ---- v path: img, d-tile ----
    const int v = bx - 741;
    const int img = v / 8, dt = v % 8;
    const size_t wbase = (size_t)ND * NC;   // W_v offset
    const size_t wrow0 = wbase + (size_t)(dt * 16 + ln) * NC + q * 8;
    floatx4 acc[13];
    #pragma unroll
    for (int nt = 0; nt < 13; ++nt) acc[nt] = (floatx4){0.f, 0.f, 0.f, 0.f};

    for (int ks = 0; ks < 16; ++ks) {
      const short8 ah = *(const short8*)(Whi + wrow0 + ks * 32);
      const short8 al = *(const short8*)(Wlo + wrow0 + ks * 32);
      #pragma unroll
      for (int nt = 0; nt < 13; ++nt) {
        const size_t xrow = ((size_t)img * JS + nt * 16 + ln) * NC + ks * 32 + q * 8;
        const short8 bh = *(const short8*)(Xhi + xrow);
        const short8 bl = *(const short8*)(Xlo + xrow);
        acc[nt] = __builtin_amdgcn_mfma_f32_16x16x32_bf16(al, bh, acc[nt], 0, 0, 0);
        acc[nt] = __builtin_amdgcn_mfma_f32_16x16x32_bf16(ah, bl, acc[nt], 0, 0, 0);
        acc[nt] = __builtin_amdgcn_mfma_f32_16x16x32_bf16(ah, bh, acc[nt], 0, 0, 0);
      }
    }
    // D row = d = dt*16 + q*4 + r, col = p = nt*16 + ln
    if (img < NB) {
      #pragma unroll
      for (int nt = 0; nt < 13; ++nt) {
        const int p = nt * 16 + ln;
        if (p < NP) {
          #pragma unroll
          for (int r = 0; r < 4; ++r) {
            const int d = dt * 16 + q * 4 + r;
            outVq[((size_t)img * ND + d) * NP + p] = acc[nt][r];
          }
        }
      }
    } else {
      const int n = img - NB;
      #pragma unroll
      for (int nt = 0; nt < 13; ++nt) {
        const int p = nt * 16 + ln;             // 0..207, pad cols masked in attn
        #pragma unroll
        for (int r = 0; r < 4; ++r) {
          const int d = dt * 16 + q * 4 + r;
          Vt[((size_t)n * ND + d) * JS + p] = (uint16_t)f2bf(acc[nt][r]);
        }
      }
    }
  }
}

// ---------------------------------------------------------------------------
// Kernel 2: per-class masked attention, single-pass (no row-max; fixed SHIFT),
// bf16 MFMA 16x16x32. One wave per (b, class, 16-row p-tile):
// grid = 32*5*13 = 2080 blocks x 64 threads.
// QK: A=Q (m=p), B=K (n=j) -> D row=p col=j. P chunk through LDS.
// PV: A=V (m=d), B=P (n=p) -> D row=d col=p -> coalesced fp32 stores.
// ---------------------------------------------------------------------------
__global__ __launch_bounds__(64) void attn_kernel(
    const uint16_t* __restrict__ Qt, const uint16_t* __restrict__ Kt,
    const uint16_t* __restrict__ Vt, const int* __restrict__ labels,
    float* __restrict__ out)
{
  __shared__ float chunk[16 * 36];   // 16 p-rows x 32 cols, pitch 36
  __shared__ float sArr[16];
  __shared__ int cls[8];

  const int bx = blockIdx.x;
  const int b   = bx / 65;
  const int rem = bx % 65;
  const int kc  = rem / 13;
  const int pt  = rem % 13;
  const int p0  = pt * 16;

  const int lane = (int)threadIdx.x;
  const int ln   = lane & 15;
  const int q    = lane >> 4;

  if (lane == 0) {
    int m = 0;
    #pragma unroll
    for (int i = 0; i < 8; ++i) cls[i] = 0;
    for (int n = 0; n < NSUP; ++n)
      if (labels[n] == kc && m < 5) cls[m++] = n;
  }
  __syncthreads();

  // Q A-fragments (resident): A[m=p][k], 4 k-windows of 32 over d=128
  short8 aq[4];
  {
    int p = p0 + ln; if (p > NP - 1) p = NP - 1;
    const uint16_t* base = Qt + ((size_t)b * NP + p) * ND + q * 8;
    #pragma unroll
    for (int ks = 0; ks < 4; ++ks) aq[ks] = *(const short8*)(base + ks * 32);
  }

  floatx4 acc[8];
  #pragma unroll
  for (int dt = 0; dt < 8; ++dt) acc[dt] = (floatx4){0.f, 0.f, 0.f, 0.f};
  float Ssum[4] = {0.f, 0.f, 0.f, 0.f};

  for (int it = 0; it < NCHUNK; ++it) {
    // --- QK + exp for the 32-col chunk ---
    #pragma unroll
    for (int t = 0; t < 2; ++t) {
      const int col = it * 32 + t * 16 + ln;
      int s = col / JS; if (s > 4) s = 4;
      int j = col - s * JS; if (j > JS - 1) j = JS - 1;
      const bool valid = (col < CLS_COLS) && (j < NP);
      const uint16_t* kb = Kt + ((size_t)(cls[s] * JS + j)) * ND + q * 8;
      floatx4 d = {0.f, 0.f, 0.f, 0.f};
      #pragma unroll
      for (int ks = 0; ks < 4; ++ks)
        d = __builtin_amdgcn_mfma_f32_16x16x32_bf16(aq[ks], *(const short8*)(kb + ks * 32), d, 0, 0, 0);
      #pragma unroll
      for (int r = 0; r < 4; ++r) {
        const float ev = valid ? __expf(d[r] - SHIFT) : 0.f;
        Ssum[r] += ev;
        chunk[(q * 4 + r) * 36 + t * 16 + ln] = ev;   // D-layout write
      }
    }
    __syncthreads();

    // --- P B-frag (B[n=p][k=j]): 8 contiguous floats -> bf16 ---
    const float* src = &chunk[ln * 36 + q * 8];
    short8 bp;
    #pragma unroll
    for (int x = 0; x < 8; ++x) bp[x] = f2bf(src[x]);

    // --- V A-frags (A[m=d][k=j]) and PV ---
    const int jjg = it * 32 + q * 8;
    int s2 = jjg / JS; if (s2 > 4) s2 = 4;
    int j2 = jjg - s2 * JS; if (j2 > JS - 8) j2 = JS - 8;  // pad: weights are 0
    const size_t vbase = (size_t)cls[s2] * ND;
    #pragma unroll
    for (int dt = 0; dt < 8; ++dt) {
      const short8 av = *(const short8*)(Vt + (vbase + dt * 16 + ln) * JS + j2);
      acc[dt] = __builtin_amdgcn_mfma_f32_16x16x32_bf16(av, bp, acc[dt], 0, 0, 0);
    }
    __syncthreads();
  }

  // --- normalize: invS per p-row, broadcast via LDS ---
  #pragma unroll
  for (int r = 0; r < 4; ++r) {
    float sv = Ssum[r];
    sv += __shfl_xor(sv, 1);
    sv += __shfl_xor(sv, 2);
    sv += __shfl_xor(sv, 4);
    sv += __shfl_xor(sv, 8);
    if (ln == 0) sArr[q * 4 + r] = 1.f / sv;
  }
  __syncthreads();

  const float f = sArr[ln];       // invS for p-row = p0 + ln
  const int p = p0 + ln;
  if (p < NP) {
    float* obase = out + ((size_t)(b * KCLS + kc) * ND) * NP + p;
    #pragma unroll
    for (int dt = 0; dt < 8; ++dt)
      #pragma unroll
      for (int r = 0; r < 4; ++r)
        obase[(size_t)(dt * 16 + q * 4 + r) * NP] = acc[dt][r] * f;
  }
}

// ---------------------------------------------------------------------------
extern "C" void kernel_launch(void* const* d_in, const int* in_sizes, int n_in,
                              void* d_out, int out_size, void* d_ws, size_t ws_size,
                              hipStream_t stream) {
  const float* supp   = (const float*)d_in[0];
  const float* qry    = (const float*)d_in[1];
  const int*   labels = (const int*)d_in[2];
  const float* Wqk    = (const float*)d_in[3];
  const float* Wv     = (const float*)d_in[4];
  float* out = (float*)d_out;

  // ws layout (all bf16 as uint16): ~29 MB
  uint16_t* Xhi = (uint16_t*)d_ws;
  uint16_t* Xlo = Xhi + (size_t)NIMG * JS * NC;     // 57*208*512
  uint16_t* Whi = Xlo + (size_t)NIMG * JS * NC;
  uint16_t* Wlo = Whi + (size_t)2 * ND * NC;
  uint16_t* Qt  = Wlo + (size_t)2 * ND * NC;        // [32][196][128]
  uint16_t* Kt  = Qt  + (size_t)NB * NP * ND;       // [25][208][128]
  uint16_t* Vt  = Kt  + (size_t)NSUP * JS * ND;     // [25][128][208]
  float* outVq = out + (size_t)NB * KCLS * ND * NP; // query_v_flat region

  conv_kernel<<<458, 256, 0, stream>>>(supp, qry, Wqk, Wv, Xhi, Xlo, Whi, Wlo);
  gemm_kernel<<<1197, 64, 0, stream>>>(Xhi, Xlo, Whi, Wlo, Qt, Kt, Vt, outVq);
  attn_kernel<<<2080, 64, 0, stream>>>(Qt, Kt, Vt, labels, out);
}

// Round 3
// 269.955 us; speedup vs baseline: 1.3451x; 1.3451x over previous
//
#include <hip/hip_runtime.h>
#include <cstdint>
#include <cstddef>

// Problem constants
#define NB   32    // query batch
#define NSUP 25    // support images
#define KCLS 5     // classes
#define NC   512   // input channels
#define ND   128   // dk = dv
#define NP   196   // h*w
#define JS   208   // per-support padded row/col count (13*16)
#define NIMG 57    // 32 query + 25 support
#define SHIFT 8.0f // fixed logit shift (softmax-invariant overflow guard)

#define QKW (NIMG*13*4)   // 2964 qk wave-tiles (img x 13 p-tiles x 4 K-parts)
#define VW  (NIMG*8*4)    // 1824 v wave-tiles  (img x 8 d-tiles x 4 K-parts)
#define NA4 (NIMG*JS*ND/4) // 379392 fixup quads per domain

typedef __attribute__((ext_vector_type(8))) short short8;   // 8 x bf16
typedef __attribute__((ext_vector_type(4))) float floatx4;  // MFMA C/D

struct alignas(8) us4 { uint16_t x, y, z, w; };

__device__ inline short f2bf(float x) {
  union { float f; uint32_t u; } v; v.f = x;
  uint32_t r = (v.u + 0x7FFFu + ((v.u >> 16) & 1u)) >> 16;  // RNE
  return (short)(r & 0xFFFFu);
}
__device__ inline float bf2f(short h) {
  union { uint32_t u; float f; } v; v.u = ((uint32_t)(uint16_t)h) << 16;
  return v.f;
}

// ---------------------------------------------------------------------------
// Kernel 0: fp32 -> bf16 hi/lo convert + transpose.
//   Xhi/Xlo[img][pp:208][c:512] (c-contig; pad rows = copy of row 195)
//   Whi/Wlo[mat][d:128][c:512]
// grid = 57*16 + 2 = 914 blocks x 256 threads (32-c slabs -> 26.8 KB LDS).
// ---------------------------------------------------------------------------
__global__ __launch_bounds__(256) void conv_kernel(
    const float* __restrict__ supp, const float* __restrict__ qry,
    const float* __restrict__ Wqk, const float* __restrict__ Wv,
    uint16_t* __restrict__ Xhi, uint16_t* __restrict__ Xlo,
    uint16_t* __restrict__ Whi, uint16_t* __restrict__ Wlo)
{
  const int bx = blockIdx.x, tid = (int)threadIdx.x;
  if (bx >= 912) {                    // W conversion
    const int mat = bx - 912;
    const float* __restrict__ W = mat ? Wv : Wqk;
    uint16_t* dh = Whi + (size_t)mat * ND * NC;
    uint16_t* dl = Wlo + (size_t)mat * ND * NC;
    for (int i = tid; i < ND * NC; i += 256) {
      const float x = W[i];
      const short h = f2bf(x);
      dh[i] = (uint16_t)h;
      dl[i] = (uint16_t)f2bf(x - bf2f(h));
    }
    return;
  }
  __shared__ float lds[32 * 209];
  const int img = bx >> 4, c0 = (bx & 15) * 32;
  const float* __restrict__ X = (img < NB)
      ? (qry  + (size_t)img * NC * NP)
      : (supp + (size_t)(img - NB) * NC * NP);
  for (int idx = tid; idx < 32 * JS; idx += 256) {   // read [c][p] coalesced
    const int cc = idx / JS, pp = idx - cc * JS;
    lds[cc * 209 + pp] = X[(c0 + cc) * NP + (pp < NP ? pp : NP - 1)];
  }
  __syncthreads();
  for (int idx = tid; idx < 32 * JS; idx += 256) {   // write [p][c] coalesced
    const int cc = idx & 31, pp = idx >> 5;
    const float x = lds[cc * 209 + pp];
    const short h = f2bf(x);
    const size_t o = ((size_t)img * JS + pp) * NC + c0 + cc;
    Xhi[o] = (uint16_t)h;
    Xlo[o] = (uint16_t)f2bf(x - bf2f(h));
  }
}

// ---------------------------------------------------------------------------
// Kernel 1: projection GEMM, K-split 4-way into fp32 partials (4788 waves).
// qk path (1-term bf16): A=X[p][c], B=Wqk[d][c] -> Pqk[part][img][p:208][d]
// v  path (3-term hi/lo): A=Wv[d][c], B=X[p][c] -> Pv[part][img][d][p:208]
// ---------------------------------------------------------------------------
__global__ __launch_bounds__(64) void gemm_kernel(
    const uint16_t* __restrict__ Xhi, const uint16_t* __restrict__ Xlo,
    const uint16_t* __restrict__ Whi, const uint16_t* __restrict__ Wlo,
    float* __restrict__ Pqk, float* __restrict__ Pv)
{
  const int bx = blockIdx.x;
  const int lane = (int)threadIdx.x;
  const int ln = lane & 15, q = lane >> 4;

  if (bx < QKW) {
    const int part = bx & 3, idx = bx >> 2;
    const int t16 = idx % 13, img = idx / 13;
    const int c0 = part * 128;
    const size_t xbase = ((size_t)img * JS + t16 * 16 + ln) * NC + c0 + q * 8;
    floatx4 acc[8];
    #pragma unroll
    for (int nt = 0; nt < 8; ++nt) acc[nt] = (floatx4){0.f, 0.f, 0.f, 0.f};
    #pragma unroll
    for (int ks = 0; ks < 4; ++ks) {
      const short8 ah = *(const short8*)(Xhi + xbase + ks * 32);
      #pragma unroll
      for (int nt = 0; nt < 8; ++nt) {
        const short8 bh = *(const short8*)(Whi + (size_t)(nt * 16 + ln) * NC + c0 + ks * 32 + q * 8);
        acc[nt] = __builtin_amdgcn_mfma_f32_16x16x32_bf16(ah, bh, acc[nt], 0, 0, 0);
      }
    }
    float* dst = Pqk + ((size_t)part * NIMG + img) * JS * ND;
    #pragma unroll
    for (int nt = 0; nt < 8; ++nt)
      #pragma unroll
      for (int rr = 0; rr < 4; ++rr)
        dst[(size_t)(t16 * 16 + q * 4 + rr) * ND + nt * 16 + ln] = acc[nt][rr];
  } else {
    const int v = bx - QKW;
    const int part = v & 3, idx = v >> 2;
    const int dt = idx % 8, img = idx / 8;
    const int c0 = part * 128;
    const size_t wbase = (size_t)ND * NC + (size_t)(dt * 16 + ln) * NC + c0 + q * 8;
    floatx4 acc[13];
    #pragma unroll
    for (int nt = 0; nt < 13; ++nt) acc[nt] = (floatx4){0.f, 0.f, 0.f, 0.f};
    #pragma unroll
    for (int ks = 0; ks < 4; ++ks) {
      const short8 ah = *(const short8*)(Whi + wbase + ks * 32);
      const short8 al = *(const short8*)(Wlo + wbase + ks * 32);
      #pragma unroll
      for (int nt = 0; nt < 13; ++nt) {
        const size_t xr = ((size_t)img * JS + nt * 16 + ln) * NC + c0 + ks * 32 + q * 8;
        const short8 bh = *(const short8*)(Xhi + xr);
        const short8 bl = *(const short8*)(Xlo + xr);
        acc[nt] = __builtin_amdgcn_mfma_f32_16x16x32_bf16(ah, bh, acc[nt], 0, 0, 0);
        acc[nt] = __builtin_amdgcn_mfma_f32_16x16x32_bf16(ah, bl, acc[nt], 0, 0, 0);
        acc[nt] = __builtin_amdgcn_mfma_f32_16x16x32_bf16(al, bh, acc[nt], 0, 0, 0);
      }
    }
    float* dst = Pv + ((size_t)part * NIMG + img) * ND * JS;
    #pragma unroll
    for (int nt = 0; nt < 13; ++nt)
      #pragma unroll
      for (int rr = 0; rr < 4; ++rr)
        dst[(size_t)(dt * 16 + q * 4 + rr) * JS + nt * 16 + ln] = acc[nt][rr];
  }
}

// ---------------------------------------------------------------------------
// Kernel 2: K-split fixup. Sums 4 fp32 partials, emits bf16 Qt/Kt/Vt and
// fp32 outVq. grid = 2964 x 256 (exactly covers both domains, float4/thread).
// ---------------------------------------------------------------------------
__global__ __launch_bounds__(256) void fix_kernel(
    const float* __restrict__ Pqk, const float* __restrict__ Pv,
    uint16_t* __restrict__ Qt, uint16_t* __restrict__ Kt,
    uint16_t* __restrict__ Vt, float* __restrict__ outVq)
{
  const int i = blockIdx.x * 256 + (int)threadIdx.x;
  const size_t SP = (size_t)NIMG * JS * ND;   // per-part stride (both domains)
  if (i < NA4) {
    const size_t e = (size_t)i * 4;
    floatx4 s = *(const floatx4*)(Pqk + e);
    s += *(const floatx4*)(Pqk + e + SP);
    s += *(const floatx4*)(Pqk + e + 2 * SP);
    s += *(const floatx4*)(Pqk + e + 3 * SP);
    const int ei = (int)e;
    const int img = ei / (JS * ND), rem = ei % (JS * ND);
    const int p = rem / ND, d0 = rem % ND;
    us4 pk; pk.x = (uint16_t)f2bf(s[0]); pk.y = (uint16_t)f2bf(s[1]);
    pk.z = (uint16_t)f2bf(s[2]); pk.w = (uint16_t)f2bf(s[3]);
    if (img < NB) {
      if (p < NP) *(us4*)&Qt[((size_t)img * NP + p) * ND + d0] = pk;
    } else {
      *(us4*)&Kt[((size_t)(img - NB) * JS + p) * ND + d0] = pk;
    }
  } else {
    const size_t e = (size_t)(i - NA4) * 4;
    floatx4 s = *(const floatx4*)(Pv + e);
    s += *(const floatx4*)(Pv + e + SP);
    s += *(const floatx4*)(Pv + e + 2 * SP);
    s += *(const floatx4*)(Pv + e + 3 * SP);
    const int ei = (int)e;
    const int img = ei / (ND * JS), rem = ei % (ND * JS);
    const int d = rem / JS, pp = rem % JS;
    if (img < NB) {
      if (pp < NP) *(floatx4*)&outVq[((size_t)img * ND + d) * NP + pp] = s;
    } else {
      us4 pk; pk.x = (uint16_t)f2bf(s[0]); pk.y = (uint16_t)f2bf(s[1]);
      pk.z = (uint16_t)f2bf(s[2]); pk.w = (uint16_t)f2bf(s[3]);
      *(us4*)&Vt[((size_t)(img - NB) * ND + d) * JS + pp] = pk;
    }
  }
}

// ---------------------------------------------------------------------------
// Kernel 3: per-class masked attention, 4 waves/block (j-split), no in-loop
// barriers (per-wave LDS P-buffers), LDS merge at end.
// grid = 32*5*13 = 2080 blocks x 256 threads.
// ---------------------------------------------------------------------------
__global__ __launch_bounds__(256) void attn_kernel(
    const uint16_t* __restrict__ Qt, const uint16_t* __restrict__ Kt,
    const uint16_t* __restrict__ Vt, const int* __restrict__ labels,
    float* __restrict__ out)
{
  __shared__ float chunkBuf[4][16 * 33];     // per-wave P chunk (pitch 33)
  __shared__ float mergeAcc[4][4][256];      // [dt-in-round][wave][lane*4]
  __shared__ float sS[4][16];

  const int bx = blockIdx.x;
  const int b = bx / 65, rem = bx % 65;
  const int kc = rem / 13, pt = rem % 13, p0 = pt * 16;
  const int tid = (int)threadIdx.x;
  const int w = tid >> 6, lane = tid & 63, ln = lane & 15, q = lane >> 4;

  // class-support list packed in a register (6 bits per slot)
  const int myl = (lane < NSUP) ? labels[lane] : -1;
  unsigned long long m = __ballot(myl == kc);
  int clsPack = 0;
  #pragma unroll
  for (int s = 0; s < 5; ++s) {
    const int n = (m != 0ull) ? (int)__builtin_ctzll(m) : 0;
    clsPack |= n << (6 * s);
    m &= (m - 1);
  }

  // Q A-fragments (resident)
  short8 aq[4];
  {
    int p = p0 + ln; if (p > NP - 1) p = NP - 1;
    const uint16_t* base = Qt + ((size_t)b * NP + p) * ND + q * 8;
    #pragma unroll
    for (int ks = 0; ks < 4; ++ks) aq[ks] = *(const short8*)(base + ks * 32);
  }

  floatx4 acc[8];
  #pragma unroll
  for (int dt = 0; dt < 8; ++dt) acc[dt] = (floatx4){0.f, 0.f, 0.f, 0.f};
  float Ssum[4] = {0.f, 0.f, 0.f, 0.f};
  float* cb = chunkBuf[w];

  for (int it = w; it < 33; it += 4) {       // this wave's 32-col chunks
    // K fragments for both 16-tiles (each 16-tile lies in one support)
    short8 bk[2][4];
    bool vcol[2];
    #pragma unroll
    for (int t = 0; t < 2; ++t) {
      const int tile16 = it * 2 + t;
      const int s = tile16 / 13;             // 0..5 (5 = pad tile)
      const int j0 = (tile16 - s * 13) * 16;
      const int se = s < 5 ? s : 4;
      const int n = (clsPack >> (6 * se)) & 63;
      vcol[t] = (s < 5) && (j0 + ln < NP);
      const uint16_t* kp = Kt + ((size_t)n * JS + j0 + ln) * ND + q * 8;
      #pragma unroll
      for (int ks = 0; ks < 4; ++ks) bk[t][ks] = *(const short8*)(kp + ks * 32);
    }
    // V fragments (independent of P; issue early)
    const int jj = it * 32 + q * 8;
    int s2 = jj / JS; if (s2 > 4) s2 = 4;
    int j2 = jj - s2 * JS; if (j2 > JS - 8) j2 = JS - 8;  // pad lanes: weight=0
    const int n2 = (clsPack >> (6 * s2)) & 63;
    short8 av[8];
    #pragma unroll
    for (int dt = 0; dt < 8; ++dt)
      av[dt] = *(const short8*)(Vt + ((size_t)n2 * ND + dt * 16 + ln) * JS + j2);

    // QK -> exp -> per-wave LDS chunk (D-layout write)
    #pragma unroll
    for (int t = 0; t < 2; ++t) {
      floatx4 d4 = {0.f, 0.f, 0.f, 0.f};
      #pragma unroll
      for (int ks = 0; ks < 4; ++ks)
        d4 = __builtin_amdgcn_mfma_f32_16x16x32_bf16(aq[ks], bk[t][ks], d4, 0, 0, 0);
      #pragma unroll
      for (int r = 0; r < 4; ++r) {
        const float ev = vcol[t] ? __expf(d4[r] - SHIFT) : 0.f;
        Ssum[r] += ev;
        cb[(q * 4 + r) * 33 + t * 16 + ln] = ev;
      }
    }
    // B-frag read (A-layout) + convert; intra-wave lgkmcnt ordering only
    const float* src = cb + ln * 33 + q * 8;
    short8 bp;
    #pragma unroll
    for (int x = 0; x < 8; ++x) bp[x] = f2bf(src[x]);
    #pragma unroll
    for (int dt = 0; dt < 8; ++dt)
      acc[dt] = __builtin_amdgcn_mfma_f32_16x16x32_bf16(av[dt], bp, acc[dt], 0, 0, 0);
  }

  // ---- merge across the 4 waves ----
  #pragma unroll
  for (int r = 0; r < 4; ++r) {
    float sv = Ssum[r];
    sv += __shfl_xor(sv, 1); sv += __shfl_xor(sv, 2);
    sv += __shfl_xor(sv, 4); sv += __shfl_xor(sv, 8);
    if (ln == 0) sS[w][q * 4 + r] = sv;
  }
  #pragma unroll
  for (int g = 0; g < 4; ++g)
    *(floatx4*)&mergeAcc[g][w][lane * 4] = acc[g];
  __syncthreads();

  const float invS = 1.f / (sS[0][ln] + sS[1][ln] + sS[2][ln] + sS[3][ln]);
  const int p = p0 + ln;
  {
    floatx4 v = *(const floatx4*)&mergeAcc[w][0][lane * 4];
    v += *(const floatx4*)&mergeAcc[w][1][lane * 4];
    v += *(const floatx4*)&mergeAcc[w][2][lane * 4];
    v += *(const floatx4*)&mergeAcc[w][3][lane * 4];
    if (p < NP) {
      float* ob = out + ((size_t)(b * KCLS + kc) * ND + w * 16 + q * 4) * NP + p;
      #pragma unroll
      for (int rr = 0; rr < 4; ++rr) ob[(size_t)rr * NP] = v[rr] * invS;
    }
  }
  __syncthreads();
  #pragma unroll
  for (int g = 0; g < 4; ++g)
    *(floatx4*)&mergeAcc[g][w][lane * 4] = acc[4 + g];
  __syncthreads();
  {
    floatx4 v = *(const floatx4*)&mergeAcc[w][0][lane * 4];
    v += *(const floatx4*)&mergeAcc[w][1][lane * 4];
    v += *(const floatx4*)&mergeAcc[w][2][lane * 4];
    v += *(const floatx4*)&mergeAcc[w][3][lane * 4];
    if (p < NP) {
      float* ob = out + ((size_t)(b * KCLS + kc) * ND + (4 + w) * 16 + q * 4) * NP + p;
      #pragma unroll
      for (int rr = 0; rr < 4; ++rr) ob[(size_t)rr * NP] = v[rr] * invS;
    }
  }
}

// ---------------------------------------------------------------------------
extern "C" void kernel_launch(void* const* d_in, const int* in_sizes, int n_in,
                              void* d_out, int out_size, void* d_ws, size_t ws_size,
                              hipStream_t stream) {
  const float* supp   = (const float*)d_in[0];
  const float* qry    = (const float*)d_in[1];
  const int*   labels = (const int*)d_in[2];
  const float* Wqk    = (const float*)d_in[3];
  const float* Wv     = (const float*)d_in[4];
  float* out = (float*)d_out;

  // ws layout (~77.6 MB)
  uint16_t* Xhi = (uint16_t*)d_ws;
  uint16_t* Xlo = Xhi + (size_t)NIMG * JS * NC;
  uint16_t* Whi = Xlo + (size_t)NIMG * JS * NC;
  uint16_t* Wlo = Whi + (size_t)2 * ND * NC;
  uint16_t* Qt  = Wlo + (size_t)2 * ND * NC;        // [32][196][128]
  uint16_t* Kt  = Qt  + (size_t)NB * NP * ND;       // [25][208][128]
  uint16_t* Vt  = Kt  + (size_t)NSUP * JS * ND;     // [25][128][208]
  float* Pqk = (float*)(Vt + (size_t)NSUP * ND * JS);
  float* Pv  = Pqk + (size_t)4 * NIMG * JS * ND;
  float* outVq = out + (size_t)NB * KCLS * ND * NP; // query_v_flat region

  conv_kernel<<<914, 256, 0, stream>>>(supp, qry, Wqk, Wv, Xhi, Xlo, Whi, Wlo);
  gemm_kernel<<<QKW + VW, 64, 0, stream>>>(Xhi, Xlo, Whi, Wlo, Pqk, Pv);
  fix_kernel<<<2964, 256, 0, stream>>>(Pqk, Pv, Qt, Kt, Vt, outVq);
  attn_kernel<<<2080, 256, 0, stream>>>(Qt, Kt, Vt, labels, out);
}